// Round 7
// baseline (227.053 us; speedup 1.0000x reference)
//
#include <hip/hip_runtime.h>
#include <math.h>

#define EPS 1.1920928955078125e-07f   // jnp.finfo(f32).eps

typedef __attribute__((ext_vector_type(8)))  short short8;
typedef __attribute__((ext_vector_type(4)))  short short4v;
typedef __attribute__((ext_vector_type(16))) float floatx16;

__device__ __forceinline__ float4 ld4(const float* __restrict__ p) { return *(const float4* __restrict__)p; }
__device__ __forceinline__ void   st4(float* __restrict__ p, float4 v) { *(float4* __restrict__)p = v; }

// f32 -> bf16 round-to-nearest-even
__device__ __forceinline__ unsigned short f2bf(float f) {
    union { float f; unsigned u; } v; v.f = f;
    unsigned r = v.u + 0x7fffu + ((v.u >> 16) & 1u);
    return (unsigned short)(r >> 16);
}

// ---------------------------------------------------------------------------
// Kernel 1: pack W (MFMA B-frag layout) + embedding->bf16, one launch.
// blocks 0..79: WbF; blocks 80..591: ebf
// ---------------------------------------------------------------------------
__global__ __launch_bounds__(256) void build_pack(const float* __restrict__ val_W,
                                                  const float* __restrict__ key_W,
                                                  const float* __restrict__ emb,
                                                  unsigned short* __restrict__ WbF,
                                                  unsigned short* __restrict__ ebf)
{
    int bid = blockIdx.x;
    if (bid < 80) {
        int idx  = bid * 256 + threadIdx.x;           // 0 .. 20479
        int lane = idx & 63;
        int ks   = (idx >> 6) & 15;
        int nt   = idx >> 10;
        int n = (nt << 5) + (lane & 31);
        int k = (ks << 4) + ((lane >> 5) << 3);
        const float* src = (n < 512) ? key_W + (size_t)n * 256 + k
                                     : val_W + (size_t)(n - 512) * 256 + k;
        float4 v0 = ld4(src), v1 = ld4(src + 4);
        unsigned short o[8] = { f2bf(v0.x), f2bf(v0.y), f2bf(v0.z), f2bf(v0.w),
                                f2bf(v1.x), f2bf(v1.y), f2bf(v1.z), f2bf(v1.w) };
        unsigned short* dst = WbF + (size_t)idx * 8;
        *(short4v*)dst       = *(short4v*)&o[0];
        *(short4v*)(dst + 4) = *(short4v*)&o[4];
    } else {
        int idx = (bid - 80) * 256 + threadIdx.x;     // < 131072
        const float* src = emb + ((size_t)idx << 3);
        float4 v0 = ld4(src), v1 = ld4(src + 4);
        unsigned short o[8] = { f2bf(v0.x), f2bf(v0.y), f2bf(v0.z), f2bf(v0.w),
                                f2bf(v1.x), f2bf(v1.y), f2bf(v1.z), f2bf(v1.w) };
        unsigned short* dst = ebf + ((size_t)idx << 3);
        *(short4v*)dst       = *(short4v*)&o[0];
        *(short4v*)(dst + 4) = *(short4v*)&o[4];
    }
}

// ---------------------------------------------------------------------------
// Kernel 2: hash + gather(bf16) + MFMA GEMM, 32-token tile, ALL 20 n-tiles
// per block (R2 structure, verbatim — 41-43 us, VGPR 52, no spill). FROZEN.
// ---------------------------------------------------------------------------
__global__ __launch_bounds__(256, 4) void engram_gemm(
    const float* __restrict__ x,
    const int*   __restrict__ input_ids,
    const int*   __restrict__ mult,
    const unsigned short* __restrict__ ebf,
    const float* __restrict__ val_b,
    const float* __restrict__ key_b,
    const float* __restrict__ normq_w,
    const float* __restrict__ normk_w,
    const unsigned short* __restrict__ WbF,
    float* __restrict__ v_base,
    float* __restrict__ Gbuf,
    float* __restrict__ S2buf)
{
    __shared__ int   sids[32][4];
    __shared__ short A[32 * 260];    // bf16 A [32][260], live for all 5 passes
    __shared__ float D[32 * 130];    // f32 D slab [32][130], reused per pass

    const int tid  = threadIdx.x;
    const int tok0 = blockIdx.x << 5;

    if (tid < 32) {
        int token = tok0 + tid;
        int b = token >> 12, t = token & 4095;
        const int* row = input_ids + (b << 12);
        unsigned g2 = (unsigned)row[t];
        unsigned g1 = (t >= 1) ? (unsigned)row[t - 1] : 0u;
        unsigned g0 = (t >= 2) ? (unsigned)row[t - 2] : 0u;
        sids[tid][0] = (int)(((g1 * (unsigned)mult[0]) ^ (g2 * (unsigned)mult[1])) & 4095u);
        sids[tid][1] = (int)((((g1 * (unsigned)mult[3]) ^ (g2 * (unsigned)mult[4])) & 4095u) + 4096u);
        sids[tid][2] = (int)((((g0 * (unsigned)mult[6]) ^ (g1 * (unsigned)mult[7]) ^ (g2 * (unsigned)mult[8])) & 4095u) + 8192u);
        sids[tid][3] = (int)((((g0 * (unsigned)mult[9]) ^ (g1 * (unsigned)mult[10]) ^ (g2 * (unsigned)mult[11])) & 4095u) + 12288u);
    }
    __syncthreads();

    // stage A: 32 tokens x 32 chunks(8 bf16) -> 4 per thread (ONCE per tile)
    #pragma unroll
    for (int it = 0; it < 4; ++it) {
        int f = (it << 8) + tid;
        int token = f >> 5, ch = f & 31;
        const unsigned short* src = ebf + ((size_t)sids[token][ch >> 3] << 6) + ((ch & 7) << 3);
        short4v lo = *(const short4v*)src;
        short4v hi = *(const short4v*)(src + 4);
        short* dst = A + token * 260 + (ch << 3);
        *(short4v*)dst       = lo;
        *(short4v*)(dst + 4) = hi;
    }
    __syncthreads();

    const int lane = tid & 63;
    const int wv   = tid >> 6;
    const int half = lane >> 5;
    const int mrow = lane & 31;

    const short*  Ap = A + mrow * 260 + (half << 3);
    const float4* Bf = (const float4*)WbF + lane;

    const int ty = tid >> 4, tx = tid & 15;
    const int tx8 = tx << 3;
    const int colw = (wv << 5) + mrow;
    const int rb   = half << 2;

    // ---- 4 key-stream passes ----
    for (int s = 0; s < 4; ++s) {
        // x prefetch for this stream: issued before MFMA loop, consumed after
        // two barriers -> HBM latency hides under 16 MFMAs + barriers.
        const float* xp0 = x + ((((size_t)(tok0 + (ty << 1))     << 2) + s) << 7) + tx8;
        const float* xp1 = x + ((((size_t)(tok0 + (ty << 1) + 1) << 2) + s) << 7) + tx8;
        float4 xa0 = ld4(xp0), xb0 = ld4(xp0 + 4);
        float4 xa1 = ld4(xp1), xb1 = ld4(xp1 + 4);

        floatx16 acc;
        #pragma unroll
        for (int r = 0; r < 16; ++r) acc[r] = 0.f;
        const int nt = (s << 2) + wv;
        const float4* bp = Bf + ((size_t)(nt << 4) << 6);
        #pragma unroll 4
        for (int ks = 0; ks < 16; ++ks) {
            short4v al = *(const short4v*)(Ap + (ks << 4));
            short4v ah = *(const short4v*)(Ap + (ks << 4) + 4);
            short8 a = { al[0], al[1], al[2], al[3], ah[0], ah[1], ah[2], ah[3] };
            union { float4 f; short8 s8; } ub;
            ub.f = bp[(size_t)ks << 6];
            acc = __builtin_amdgcn_mfma_f32_32x32x16_bf16(a, ub.s8, acc, 0, 0, 0);
        }

        __syncthreads();
        #pragma unroll
        for (int r = 0; r < 16; ++r) {
            int row = (r & 3) + ((r >> 2) << 3) + rb;
            D[row * 130 + colw] = acc[r];
        }
        __syncthreads();

        const float* kbp = key_b   + (s << 7) + tx8;
        const float* nqp = normq_w + (s << 7) + tx8;
        const float* nkp = normk_w + (s << 7) + tx8;
        float4 kba = ld4(kbp), kbb = ld4(kbp + 4);
        float4 nqa = ld4(nqp), nqb = ld4(nqp + 4);
        float4 nka = ld4(nkp), nkb = ld4(nkp + 4);
        float kb[8] = {kba.x, kba.y, kba.z, kba.w, kbb.x, kbb.y, kbb.z, kbb.w};
        float nq[8] = {nqa.x, nqa.y, nqa.z, nqa.w, nqb.x, nqb.y, nqb.z, nqb.w};
        float nk[8] = {nka.x, nka.y, nka.z, nka.w, nkb.x, nkb.y, nkb.z, nkb.w};
        #pragma unroll
        for (int jj = 0; jj < 2; ++jj) {
            int t_loc = (ty << 1) + jj;
            int token = tok0 + t_loc;
            const float* dp = D + t_loc * 130 + tx8;
            float kr[8]; float ks2 = 0.f;
            #pragma unroll
            for (int m = 0; m < 8; ++m) { kr[m] = dp[m] + kb[m]; ks2 += kr[m] * kr[m]; }
            float xv[8];
            if (jj == 0) { xv[0]=xa0.x; xv[1]=xa0.y; xv[2]=xa0.z; xv[3]=xa0.w;
                           xv[4]=xb0.x; xv[5]=xb0.y; xv[6]=xb0.z; xv[7]=xb0.w; }
            else         { xv[0]=xa1.x; xv[1]=xa1.y; xv[2]=xa1.z; xv[3]=xa1.w;
                           xv[4]=xb1.x; xv[5]=xb1.y; xv[6]=xb1.z; xv[7]=xb1.w; }
            float xs2 = 0.f, dt = 0.f;
            #pragma unroll
            for (int m = 0; m < 8; ++m) { xs2 += xv[m] * xv[m]; dt += xv[m] * nq[m] * kr[m] * nk[m]; }
            #pragma unroll
            for (int off = 1; off < 16; off <<= 1) {
                ks2 += __shfl_xor(ks2, off);
                xs2 += __shfl_xor(xs2, off);
                dt  += __shfl_xor(dt,  off);
            }
            float sc = dt * rsqrtf(xs2 * (1.f / 128.f) + EPS)
                          * rsqrtf(ks2 * (1.f / 128.f) + EPS) * 0.08838834764831845f;
            float gate = 1.f / (1.f + __expf(-sc));
            if (tx == 0) Gbuf[(token << 2) + s] = gate;
        }
    }

    // ---- val pass ----
    {
        floatx16 acc;
        #pragma unroll
        for (int r = 0; r < 16; ++r) acc[r] = 0.f;
        const int nt = 16 + wv;
        const float4* bp = Bf + ((size_t)(nt << 4) << 6);
        #pragma unroll 4
        for (int ks = 0; ks < 16; ++ks) {
            short4v al = *(const short4v*)(Ap + (ks << 4));
            short4v ah = *(const short4v*)(Ap + (ks << 4) + 4);
            short8 a = { al[0], al[1], al[2], al[3], ah[0], ah[1], ah[2], ah[3] };
            union { float4 f; short8 s8; } ub;
            ub.f = bp[(size_t)ks << 6];
            acc = __builtin_amdgcn_mfma_f32_32x32x16_bf16(a, ub.s8, acc, 0, 0, 0);
        }
        __syncthreads();
        #pragma unroll
        for (int r = 0; r < 16; ++r) {
            int row = (r & 3) + ((r >> 2) << 3) + rb;
            D[row * 130 + colw] = acc[r];
        }
        __syncthreads();

        const float* vbp = val_b + tx8;
        float4 vba = ld4(vbp), vbb = ld4(vbp + 4);
        float vb[8] = {vba.x, vba.y, vba.z, vba.w, vbb.x, vbb.y, vbb.z, vbb.w};
        #pragma unroll
        for (int jj = 0; jj < 2; ++jj) {
            int t_loc = (ty << 1) + jj;
            int token = tok0 + t_loc;
            const float* dp = D + t_loc * 130 + tx8;
            float v[8]; float s2 = 0.f;
            #pragma unroll
            for (int m = 0; m < 8; ++m) { v[m] = dp[m] + vb[m]; s2 += v[m] * v[m]; }
            #pragma unroll
            for (int off = 1; off < 16; off <<= 1) s2 += __shfl_xor(s2, off);
            float* vp = v_base + ((size_t)token << 7) + tx8;
            st4(vp,     make_float4(v[0], v[1], v[2], v[3]));
            st4(vp + 4, make_float4(v[4], v[5], v[6], v[7]));
            if (tx == 0) S2buf[token] = s2;
        }
    }
}

// ---------------------------------------------------------------------------
// Kernel 3 (STRIP-LDS): gate/xn/conv/SiLU/residual.
// Block = 32 consecutive tokens. Phase 1: stage v rows [tok0-3, tok0+31]
// (35 x 128 f32 = 17.9 KB) into LDS once + fw per (row,s) computed ONCE
// (was 128x per value). Phase 2: thread = (16-token run, stream, d4-quad),
// rolling 4-row register window, fully unrolled (static indices, no scratch).
// v read from HBM exactly 1.09x; fw rsqrt count cut ~100x. grid 1024 x 256.
// Halo rows with seq<3: v=0 AND fw=0 (matches reference left zero-padding;
// 4096%32==0 so strips never straddle sequences).
// ---------------------------------------------------------------------------
__global__ __launch_bounds__(256, 4) void engram_out(
    const float* __restrict__ v_base,
    const float* __restrict__ Gbuf,
    const float* __restrict__ S2buf,
    const float* __restrict__ conv_w,
    const float* __restrict__ convnorm_w,
    float* __restrict__ out)
{
    __shared__ float Vs[35 * 128];   // rows tok0-3 .. tok0+31
    __shared__ float FWs[35 * 4];    // fw per (row, s)
    __shared__ float Gs[32 * 4];     // raw gate for own rows (residual)

    const int tid  = threadIdx.x;
    const int tok0 = blockIdx.x << 5;
    const int seq0 = tok0 & 4095;

    // stage v strip: 35 rows x 32 float4 = 1120 vec loads
    for (int i = tid; i < 1120; i += 256) {
        int row = i >> 5;            // 0..34
        int c4  = i & 31;
        float4 v;
        if (seq0 + row >= 3) {
            int glob = tok0 - 3 + row;
            v = ld4(v_base + ((size_t)glob << 7) + (c4 << 2));
        } else {
            v = make_float4(0.f, 0.f, 0.f, 0.f);
        }
        st4(&Vs[row * 128 + (c4 << 2)], v);
    }
    // fw (+g): 35 rows x 4 streams = 140 values, each computed once
    if (tid < 140) {
        int row = tid >> 2;          // 0..34
        int s   = tid & 3;
        float fw = 0.f, g = 0.f;
        if (seq0 + row >= 3) {
            int glob = tok0 - 3 + row;
            g = Gbuf[(glob << 2) + s];
            float s2n = S2buf[glob] * (1.f / 128.f);
            fw = g * rsqrtf(g * g * s2n + EPS);
        }
        FWs[tid] = fw;
        if (row >= 3) Gs[((row - 3) << 2) + s] = g;
    }
    __syncthreads();

    const int d4 = tid & 31;
    const int s  = (tid >> 5) & 3;
    const int t0 = (tid >> 7) << 4;  // 0 or 16: this thread's 16-token run

    const int ch0 = (s << 7) + (d4 << 2);
    float4 cwv = ld4(convnorm_w + ch0);
    float  cwn[4] = { cwv.x, cwv.y, cwv.z, cwv.w };
    float4 w0 = ld4(conv_w + (size_t)(ch0 + 0) * 4);
    float4 w1 = ld4(conv_w + (size_t)(ch0 + 1) * 4);
    float4 w2 = ld4(conv_w + (size_t)(ch0 + 2) * 4);
    float4 w3 = ld4(conv_w + (size_t)(ch0 + 3) * 4);

    // rolling window: vw[k] = Vs row (t_loc + k), fwv[k] matching fw
    float vw[4][4];
    float fwv[4];
    #pragma unroll
    for (int k = 0; k < 3; ++k) {
        const float* p = &Vs[(t0 + k) * 128 + (d4 << 2)];
        vw[k][0] = p[0]; vw[k][1] = p[1]; vw[k][2] = p[2]; vw[k][3] = p[3];
        fwv[k] = FWs[((t0 + k) << 2) + s];
    }

    #pragma unroll
    for (int t = 0; t < 16; ++t) {
        const int tl = t0 + t;
        const float* p = &Vs[(tl + 3) * 128 + (d4 << 2)];
        vw[3][0] = p[0]; vw[3][1] = p[1]; vw[3][2] = p[2]; vw[3][3] = p[3];
        fwv[3] = FWs[((tl + 3) << 2) + s];
        const float g3 = Gs[(tl << 2) + s];

        float o[4];
        #pragma unroll
        for (int i = 0; i < 4; ++i) {
            float4 wi = (i == 0) ? w0 : (i == 1) ? w1 : (i == 2) ? w2 : w3;
            float a = wi.x * vw[0][i] * fwv[0]
                    + wi.y * vw[1][i] * fwv[1]
                    + wi.z * vw[2][i] * fwv[2]
                    + wi.w * vw[3][i] * fwv[3];
            float y = a * cwn[i];
            o[i] = vw[3][i] * g3 + y / (1.f + __expf(-y));
        }
        st4(out + ((size_t)(((tok0 + tl) << 2) + s) << 7) + (d4 << 2),
            make_float4(o[0], o[1], o[2], o[3]));

        // shift window (static indices; loop fully unrolled)
        #pragma unroll
        for (int i = 0; i < 4; ++i) { vw[0][i] = vw[1][i]; vw[1][i] = vw[2][i]; vw[2][i] = vw[3][i]; }
        fwv[0] = fwv[1]; fwv[1] = fwv[2]; fwv[2] = fwv[3];
    }
}

// ---------------------------------------------------------------------------
extern "C" void kernel_launch(void* const* d_in, const int* in_sizes, int n_in,
                              void* d_out, int out_size, void* d_ws, size_t ws_size,
                              hipStream_t stream)
{
    const float* x          = (const float*)d_in[0];
    const int*   input_ids  = (const int*)d_in[1];
    const int*   mult       = (const int*)d_in[2];
    const float* embedding  = (const float*)d_in[3];
    const float* val_W      = (const float*)d_in[4];
    const float* val_b      = (const float*)d_in[5];
    const float* key_W      = (const float*)d_in[6];
    const float* key_b      = (const float*)d_in[7];
    const float* normq_w    = (const float*)d_in[8];
    const float* normk_w    = (const float*)d_in[9];
    const float* conv_w     = (const float*)d_in[10];
    const float* convnorm_w = (const float*)d_in[11];
    float* out = (float*)d_out;

    char* ws = (char*)d_ws;
    unsigned short* WbF = (unsigned short*)ws;                    // 327,680 B
    unsigned short* ebf = (unsigned short*)(ws + 327680);         // 2,097,152 B
    float* v_base = (float*)(ws + 327680 + 2097152);              // 16 MiB
    float* Gbuf   = (float*)(ws + 327680 + 2097152 + 16777216);   // 512 KiB
    float* S2buf  = (float*)(ws + 327680 + 2097152 + 16777216 + 524288); // 128 KiB

    build_pack<<<592, 256, 0, stream>>>(val_W, key_W, embedding, WbF, ebf);
    engram_gemm<<<1024, 256, 0, stream>>>(x, input_ids, mult, ebf, val_b, key_b,
                                          normq_w, normk_w, WbF, v_base, Gbuf, S2buf);
    engram_out<<<1024, 256, 0, stream>>>(v_base, Gbuf, S2buf, conv_w, convnorm_w, out);
}